// Round 5
// baseline (1956.246 us; speedup 1.0000x reference)
//
#include <hip/hip_runtime.h>
#include <hip/hip_bf16.h>

// Problem constants (F is hard-coded 31 in the reference / TAG)
#define FDIM 31
#define FPAD 32      // padded row length in elements
#define RSTRIDE 16   // row stride in uints (32 bf16 = 64 B = 16 uints = 1 cache line)

// Coarse bucketing for CSR build: 2048 nodes per bucket
#define CBITS 11
#define CW    (1 << CBITS)
#define MAXBUK 256
#define TILE 4096

// clang ext-vector types: required by __builtin_nontemporal_{load,store}
// (HIP_vector_type int4/uint4 pointers are rejected by the builtin).
typedef int      iv4 __attribute__((ext_vector_type(4)));
typedef unsigned uv4 __attribute__((ext_vector_type(4)));

// ---- bf16 pack/unpack helpers (packed as 2 bf16 per uint, little-endian)
__device__ __forceinline__ float bf_lo(unsigned u) { return __uint_as_float(u << 16); }
__device__ __forceinline__ float bf_hi(unsigned u) { return __uint_as_float(u & 0xFFFF0000u); }
__device__ __forceinline__ unsigned pack2(float lo, float hi) {
    unsigned a = __float_as_uint(lo), b = __float_as_uint(hi);
    unsigned ra = (a + 0x7FFFu + ((a >> 16) & 1u)) >> 16;   // RNE
    unsigned rb = (b + 0x7FFFu + ((b >> 16) & 1u)) >> 16;
    return ra | (rb << 16);
}

// first index in sorted gid[0..Ntot) with gid[idx] >= g
__device__ __forceinline__ int lb_gid(const int* __restrict__ gid, int Ntot, int g) {
    int lo = 0, hi = Ntot;
    while (lo < hi) { int mid = (lo + hi) >> 1; if (gid[mid] < g) lo = mid + 1; else hi = mid; }
    return lo;
}

// --------------------------------------------------- multisplit (level 1)
__global__ __launch_bounds__(256) void multisplit_kernel(
    const int* __restrict__ src, const int* __restrict__ dst,
    int* __restrict__ gcnt, int* __restrict__ bucketed,
    int cap, int E, int nbuk)
{
    __shared__ int ordered[TILE];
    __shared__ int hist[MAXBUK];
    __shared__ int lofs[MAXBUK + 1];
    __shared__ int base_[MAXBUK];
    __shared__ int cur[MAXBUK];
    const int tid = threadIdx.x;
    const int e0 = blockIdx.x * TILE;
    const int n = min(TILE, E - e0);
    if (tid < MAXBUK) hist[tid] = 0;
    __syncthreads();
    for (int i = tid; i < n; i += 256)
        atomicAdd(&hist[dst[e0 + i] >> CBITS], 1);
    __syncthreads();
    if (tid == 0) {
        int a = 0;
        for (int b = 0; b < nbuk; ++b) { lofs[b] = a; a += hist[b]; }
        lofs[nbuk] = a;
    }
    __syncthreads();
    if (tid < nbuk) {
        int h = hist[tid];
        base_[tid] = h ? atomicAdd(&gcnt[tid], h) : 0;
        cur[tid] = lofs[tid];
    }
    __syncthreads();
    for (int i = tid; i < n; i += 256) {
        int s = src[e0 + i], d = dst[e0 + i];
        int b = d >> CBITS;
        int r = atomicAdd(&cur[b], 1);
        ordered[r] = (s << CBITS) | (d & (CW - 1));
    }
    __syncthreads();
    for (int i = tid; i < n; i += 256) {
        int lo = 0, hi = nbuk;
        while (hi - lo > 1) {
            int mid = (lo + hi) >> 1;
            if (lofs[mid] <= i) lo = mid; else hi = mid;
        }
        int b = lo;
        int pos = base_[b] + (i - lofs[b]);
        if (pos < cap) bucketed[(size_t)b * cap + pos] = ordered[i];
    }
}

// ---------------------------------- tiny serial scans: gcnt->bbase, num->soff
// bbase reserves room for per-row pad-to-8 (<= 7 per node, 2048 nodes/bucket)
// and is itself kept a multiple of 8 so every row start is 8-aligned (16B col).
__global__ void small_scans_kernel(const int* __restrict__ num, int* __restrict__ soff, int Bn,
                                   const int* __restrict__ gcnt, int* __restrict__ bbase,
                                   int nbuk, int cap) {
    if (threadIdx.x == 0 && blockIdx.x == 0) {
        int acc = 0; soff[0] = 0;
        for (int i = 0; i < Bn; ++i) { acc += num[i]; soff[i + 1] = acc; }
        int a = 0;
        for (int b = 0; b < nbuk; ++b) {
            bbase[b] = a;
            a += ((min(gcnt[b], cap) + 7) & ~7) + 7 * CW;
        }
    }
}

// -------------------- per-bucket: hist + LDS scan + rowbeg/rowend/normv + CSR fill
// Rows are padded to a multiple of 8 edges; pad slots point at dummy node N
// (whose feature row is all zeros) so the SpMM loop has NO scalar tail.
__global__ __launch_bounds__(1024) void bucket_build_kernel(
    const int* __restrict__ bucketed, const int* __restrict__ gcnt,
    const int* __restrict__ bbase,
    int* __restrict__ rowbeg, int* __restrict__ rowend,
    float* __restrict__ normv, float* __restrict__ invn,
    int* __restrict__ col,
    int cap, int N, int nbuk)
{
    __shared__ int hist[CW];   // counts -> padded counts -> inclusive scan
    __shared__ int lcur[CW];   // fill cursors
    const int b = blockIdx.x, tid = threadIdx.x;
    hist[tid] = 0; hist[tid + 1024] = 0;
    __syncthreads();
    const int cnt = min(gcnt[b], cap);
    const int* reg = bucketed + (size_t)b * cap;
    for (int i = tid; i < cnt; i += 1024)
        atomicAdd(&hist[reg[i] & (CW - 1)], 1);
    __syncthreads();
    int c0 = hist[tid], c1 = hist[tid + 1024];       // real per-node counts
    int p0 = (c0 + 7) & ~7, p1 = (c1 + 7) & ~7;      // padded to multiple of 8
    __syncthreads();
    hist[tid] = p0; hist[tid + 1024] = p1;           // scan PADDED counts
    __syncthreads();
    // Hillis-Steele inclusive scan over 2048 entries with 1024 threads
    for (int off = 1; off < CW; off <<= 1) {
        int a0 = (tid >= off) ? hist[tid - off] : 0;
        int a1 = (tid + 1024 >= off) ? hist[tid + 1024 - off] : 0;
        __syncthreads();
        hist[tid] += a0; hist[tid + 1024] += a1;
        __syncthreads();
    }
    const int base = bbase[b];
    const int base_node = b << CBITS;
    int r0 = -1, r1 = -1;
    int node = base_node + tid;
    if (node < N) {
        r0 = base + hist[tid] - p0;                  // exclusive padded prefix
        rowbeg[node] = r0; rowend[node] = r0 + p0; lcur[tid] = r0;
        int cr = c0 > 0 ? c0 : 1;
        normv[node] = rsqrtf((float)cr);
        invn[node]  = sqrtf((float)cr);
    }
    node = base_node + tid + 1024;
    if (node < N) {
        r1 = base + hist[tid + 1024] - p1;
        rowbeg[node] = r1; rowend[node] = r1 + p1; lcur[tid + 1024] = r1;
        int cr = c1 > 0 ? c1 : 1;
        normv[node] = rsqrtf((float)cr);
        invn[node]  = sqrtf((float)cr);
    }
    __syncthreads();
    for (int i = tid; i < cnt; i += 1024) {
        int e = reg[i];
        int p = atomicAdd(&lcur[e & (CW - 1)], 1);
        col[p] = e >> CBITS;
    }
    // pad slots -> dummy node N (disjoint from real slots: no sync needed)
    if (r0 >= 0) for (int j = r0 + c0; j < r0 + p0; ++j) col[j] = N;
    if (r1 >= 0) for (int j = r1 + c1; j < r1 + p1; ++j) col[j] = N;
}

// ---- fp32 x -> packed bf16 PRE-SCALED rows: HA[n] = norm[n] * x[n]
// Row N (the pad target) is all zeros. HA[N] is never rewritten afterwards
// (spmm_mlp phase B only writes nodes < N), so pad-gathers stay zero all run.
__global__ void cast_x_kernel(const float* __restrict__ x, const float* __restrict__ normv,
                              unsigned* __restrict__ A, int N) {
    int idx = blockIdx.x * 256 + threadIdx.x;
    if (idx >= (N + 1) * RSTRIDE) return;
    int n = idx >> 4, q = idx & 15;
    if (n >= N) { A[idx] = 0u; return; }
    float nv = normv[n];
    int f0 = 2 * q, f1 = 2 * q + 1;
    float lo = (f0 < FDIM) ? nv * x[(size_t)n * FDIM + f0] : 0.0f;
    float hi = (f1 < FDIM) ? nv * x[(size_t)n * FDIM + f1] : 0.0f;
    A[idx] = pack2(lo, hi);
}

// ---- gather/accumulate macro bodies
#define GATHER8(HSRC, r0, r1, r2, r3, r4, r5, r6, r7, CA, CB)                    \
    r0 = *((const uint4*)(HSRC + (size_t)(CA).x * RSTRIDE) + sub);               \
    r1 = *((const uint4*)(HSRC + (size_t)(CA).y * RSTRIDE) + sub);               \
    r2 = *((const uint4*)(HSRC + (size_t)(CA).z * RSTRIDE) + sub);               \
    r3 = *((const uint4*)(HSRC + (size_t)(CA).w * RSTRIDE) + sub);               \
    r4 = *((const uint4*)(HSRC + (size_t)(CB).x * RSTRIDE) + sub);               \
    r5 = *((const uint4*)(HSRC + (size_t)(CB).y * RSTRIDE) + sub);               \
    r6 = *((const uint4*)(HSRC + (size_t)(CB).z * RSTRIDE) + sub);               \
    r7 = *((const uint4*)(HSRC + (size_t)(CB).w * RSTRIDE) + sub);

#define ACC_EDGE(vN)                                                   \
    acc0 += bf_lo(vN.x); acc1 += bf_hi(vN.x);                          \
    acc2 += bf_lo(vN.y); acc3 += bf_hi(vN.y);                          \
    acc4 += bf_lo(vN.z); acc5 += bf_hi(vN.z);                          \
    acc6 += bf_lo(vN.w); acc7 += bf_hi(vN.w);

#define ACC8(r0, r1, r2, r3, r4, r5, r6, r7)                           \
    ACC_EDGE(r0) ACC_EDGE(r1) ACC_EDGE(r2) ACC_EDGE(r3)                \
    ACC_EDGE(r4) ACC_EDGE(r5) ACC_EDGE(r6) ACC_EDGE(r7)

// ------------------------------------------------------------------ SpMM hop1
// Storage invariant: Hin rows are norm-scaled (H~ = norm .* h), so a hop is
// H~out = norm^2 .* sum(H~in[col]). Rows padded to x8 with dummy node N.
// NOTE (R3 post-mortem): the random gather runs at a ~3.7 TB/s external
// ceiling insensitive to occupancy (47->55% with zero delta) and to deeper
// per-wave pipelining (2-deep pipeline: null). Treat ~113 us as this
// kernel's floor; do not re-spend rounds here without a bytes reduction.
__global__ __launch_bounds__(256) void spmm_kernel(const unsigned* __restrict__ Hin,
                                                   unsigned* __restrict__ Hout,
                                                   const int* __restrict__ rowbeg,
                                                   const int* __restrict__ rowend,
                                                   const int* __restrict__ col,
                                                   const float* __restrict__ normv, int N) {
    int node = blockIdx.x * 64 + (threadIdx.x >> 2);
    int sub = threadIdx.x & 3;
    if (node > N) return;
    if (node == N) {                       // dummy zero row consumed by pad edges
        uv4 z = (uv4)0;
        __builtin_nontemporal_store(z, (uv4*)(Hout + (size_t)N * RSTRIDE) + sub);
        return;
    }
    int s = rowbeg[node];
    int nit = (rowend[node] - s) >> 3;
    float acc0 = 0.f, acc1 = 0.f, acc2 = 0.f, acc3 = 0.f;
    float acc4 = 0.f, acc5 = 0.f, acc6 = 0.f, acc7 = 0.f;
    if (nit > 0) {
        const iv4* cl = (const iv4*)(col + s);      // 16B-aligned (rows 8-aligned)
        iv4 ca = __builtin_nontemporal_load(cl);
        iv4 cb = __builtin_nontemporal_load(cl + 1);
        for (int it = 0; it < nit; ++it) {
            uint4 v0, v1, v2, v3, v4, v5, v6, v7;
            GATHER8(Hin, v0, v1, v2, v3, v4, v5, v6, v7, ca, cb)
            const iv4* nx = cl + ((it + 1 < nit) ? 2 : 0);
            iv4 na = __builtin_nontemporal_load(nx);
            iv4 nb = __builtin_nontemporal_load(nx + 1);
            cl += 2;
            ACC8(v0, v1, v2, v3, v4, v5, v6, v7)
            ca = na; cb = nb;
        }
    }
    float nv = normv[node];
    float nn2 = nv * nv;                   // H~out = norm^2 * sum
    uv4 o;
    o.x = pack2(nn2 * acc0, nn2 * acc1);
    o.y = pack2(nn2 * acc2, nn2 * acc3);
    o.z = pack2(nn2 * acc4, nn2 * acc5);
    o.w = pack2(nn2 * acc6, nn2 * acc7);
    __builtin_nontemporal_store(o, (uv4*)(Hout + (size_t)node * RSTRIDE) + sub);
}

// --------------------------------------------- fused SpMM hop2 + linear + relu
// Phase A (256 threads, 4 lanes/node, 64 nodes/block): hop-2 gather from Hb;
// result stays in f32 LDS (hc) -- no HC global buffer.
// Phase B (ALL 4 WAVES; R4 post-mortem: 1-of-4-wave phase B left 35 us of
// serial VALU exposed): wave w owns output COLUMNS 8w..8w+7 for all 64 nodes;
// lane n handles node n. Within a wave the W index i*31+8w+jj is UNIFORM
// (readfirstlane-pinned) -> scalar s_loads, no VGPR blowup (R8 lesson kept).
// Hazard: Ha row is read by all 4 waves but written quarter-per-wave in
// place, so ALL Ha reads are staged to regs before a __syncthreads() that
// precedes any write. Gate partials cross-wave-reduced in LDS (last layer).
__global__ __launch_bounds__(256, 5) void spmm_mlp_kernel(
    const unsigned* __restrict__ Hb,     // hop1 result (gather src + MLP input)
    unsigned* __restrict__ Ha,           // layer state (MLP input + output)
    const int* __restrict__ rowbeg,
    const int* __restrict__ rowend,
    const int* __restrict__ col,
    const float* __restrict__ normv,
    const float* __restrict__ invn,
    const float* __restrict__ W,         // this layer's 3*F*F block
    const float* __restrict__ bias,
    float* __restrict__ gatev,
    const float* __restrict__ w_gate,
    const float* __restrict__ b_gate,
    int do_gate, int N)
{
    __shared__ float hcL[64 * 33];       // stride 33: conflict-free both phases
    __shared__ float gred[256];          // gate partials (last layer only)
    const int tid = threadIdx.x;
    // ---------------- phase A: hop-2 gather -> hcL
    {
        int node = blockIdx.x * 64 + (tid >> 2);
        int sub = tid & 3;
        if (node < N) {
            int s = rowbeg[node];
            int nit = (rowend[node] - s) >> 3;
            float acc0 = 0.f, acc1 = 0.f, acc2 = 0.f, acc3 = 0.f;
            float acc4 = 0.f, acc5 = 0.f, acc6 = 0.f, acc7 = 0.f;
            if (nit > 0) {
                const iv4* cl = (const iv4*)(col + s);
                iv4 ca = __builtin_nontemporal_load(cl);
                iv4 cb = __builtin_nontemporal_load(cl + 1);
                for (int it = 0; it < nit; ++it) {
                    uint4 v0, v1, v2, v3, v4, v5, v6, v7;
                    GATHER8(Hb, v0, v1, v2, v3, v4, v5, v6, v7, ca, cb)
                    const iv4* nx = cl + ((it + 1 < nit) ? 2 : 0);
                    iv4 na = __builtin_nontemporal_load(nx);
                    iv4 nb = __builtin_nontemporal_load(nx + 1);
                    cl += 2;
                    ACC8(v0, v1, v2, v3, v4, v5, v6, v7)
                    ca = na; cb = nb;
                }
            }
            float nv = normv[node];
            float nn2 = nv * nv;
            float* hp = &hcL[(tid >> 2) * 33 + sub * 8];
            hp[0] = nn2 * acc0; hp[1] = nn2 * acc1;
            hp[2] = nn2 * acc2; hp[3] = nn2 * acc3;
            hp[4] = nn2 * acc4; hp[5] = nn2 * acc5;
            hp[6] = nn2 * acc6; hp[7] = nn2 * acc7;
        }
    }
    __syncthreads();                      // hcL ready
    // ---------------- phase B: wave = column block, lane = node
    const int ln = tid & 63;
    const int n2 = blockIdx.x * 64 + ln;
    const int jb = __builtin_amdgcn_readfirstlane((tid >> 6) * 8);  // SGPR col base
    // stage the Ha row BEFORE the barrier (in-place write hazard)
    uint4 ra[4];
    if (n2 < N) {
        const uint4* r4p = (const uint4*)(Ha + (size_t)n2 * RSTRIDE);
#pragma unroll
        for (int q = 0; q < 4; ++q) ra[q] = r4p[q];
    }
    __syncthreads();                      // all Ha reads done before any write
    float gp = 0.0f;
    if (n2 < N) {
        float out[8];
#pragma unroll
        for (int jj = 0; jj < 8; ++jj) out[jj] = 0.0f;
        // blk 0: ha (staged regs)
        {
            const unsigned* ru = (const unsigned*)ra;
            const float* Wb = W;
#pragma unroll
            for (int i = 0; i < FDIM; ++i) {
                float v = (i & 1) ? bf_hi(ru[i >> 1]) : bf_lo(ru[i >> 1]);
#pragma unroll
                for (int jj = 0; jj < 8; ++jj) {
                    int j = jb + jj; j = j < FDIM ? j : FDIM - 1;   // clamp (w3 pad)
                    out[jj] = fmaf(v, Wb[i * FDIM + j], out[jj]);
                }
            }
        }
        // blk 1: hb (global, read-only)
        {
            uint4 rb[4];
            const uint4* r4p = (const uint4*)(Hb + (size_t)n2 * RSTRIDE);
#pragma unroll
            for (int q = 0; q < 4; ++q) rb[q] = r4p[q];
            const unsigned* ru = (const unsigned*)rb;
            const float* Wb = W + FDIM * FDIM;
#pragma unroll
            for (int i = 0; i < FDIM; ++i) {
                float v = (i & 1) ? bf_hi(ru[i >> 1]) : bf_lo(ru[i >> 1]);
#pragma unroll
                for (int jj = 0; jj < 8; ++jj) {
                    int j = jb + jj; j = j < FDIM ? j : FDIM - 1;
                    out[jj] = fmaf(v, Wb[i * FDIM + j], out[jj]);
                }
            }
        }
        // blk 2: hc (LDS, f32)
        {
            const float* hp = &hcL[ln * 33];
            const float* Wb = W + 2 * FDIM * FDIM;
#pragma unroll
            for (int i = 0; i < FDIM; ++i) {
                float v = hp[i];
#pragma unroll
                for (int jj = 0; jj < 8; ++jj) {
                    int j = jb + jj; j = j < FDIM ? j : FDIM - 1;
                    out[jj] = fmaf(v, Wb[i * FDIM + j], out[jj]);
                }
            }
        }
        float inv = invn[n2];
#pragma unroll
        for (int jj = 0; jj < 8; ++jj) {
            int j = jb + jj; j = j < FDIM ? j : FDIM - 1;
            out[jj] = fmaxf(fmaf(out[jj], inv, bias[j]), 0.0f);
        }
        if (jb + 7 >= FDIM) out[7] = 0.0f;           // zero the pad column (wave 3)
        float sc = do_gate ? 1.0f : normv[n2];       // next layer wants norm-scaled
        uint4 q;
        q.x = pack2(sc * out[0], sc * out[1]);
        q.y = pack2(sc * out[2], sc * out[3]);
        q.z = pack2(sc * out[4], sc * out[5]);
        q.w = pack2(sc * out[6], sc * out[7]);
        ((uint4*)(Ha + (size_t)n2 * RSTRIDE))[jb >> 3] = q;
        if (do_gate) {
#pragma unroll
            for (int jj = 0; jj < 8; ++jj) {
                int j = jb + jj; j = j < FDIM ? j : FDIM - 1;
                gp = fmaf(out[jj], w_gate[j], gp);   // out[7]==0 on wave 3: safe
            }
        }
    }
    if (do_gate) {
        gred[tid] = gp;
        __syncthreads();
        if (tid < 64 && n2 < N)
            gatev[n2] = b_gate[0] + gred[tid] + gred[tid + 64] + gred[tid + 128] + gred[tid + 192];
    }
}

// ----------------------------------------------------------------- pooling

__global__ __launch_bounds__(64) void graph_reduce_kernel(const float* __restrict__ gate,
                                                          const int* __restrict__ gid,
                                                          const int* __restrict__ soff, int Bn,
                                                          int Ntot,
                                                          float* __restrict__ gmax,
                                                          float* __restrict__ gden) {
    int g = blockIdx.x;
    if (g >= soff[Bn]) return;
    int s = lb_gid(gid, Ntot, g), e = lb_gid(gid, Ntot, g + 1);
    float m = -1e30f;
    for (int n = s + threadIdx.x; n < e; n += 64) m = fmaxf(m, gate[n]);
#pragma unroll
    for (int o = 32; o > 0; o >>= 1) m = fmaxf(m, __shfl_xor(m, o));
    float d = 0.0f;
    for (int n = s + threadIdx.x; n < e; n += 64) d += expf(gate[n] - m);
#pragma unroll
    for (int o = 32; o > 0; o >>= 1) d += __shfl_xor(d, o);
    if (threadIdx.x == 0) { gmax[g] = m; gden[g] = d; }
}

// One block per (sample, slot); writes zeros into pad slots (replaces d_out memset).
__global__ __launch_bounds__(64) void rep_scatter_kernel(const unsigned short* __restrict__ H,
                                                         const float* __restrict__ gate,
                                                         const int* __restrict__ gid,
                                                         const int* __restrict__ soff,
                                                         int MAXG, int Ntot,
                                                         const float* __restrict__ gmax,
                                                         const float* __restrict__ gden,
                                                         float* __restrict__ out) {
    int s = blockIdx.x / MAXG;
    int pos = blockIdx.x % MAXG;
    int t = threadIdx.x;
    if (t >= FDIM) return;
    int gbeg = soff[s], gend = soff[s + 1];
    float* op = out + ((size_t)s * MAXG + pos) * FDIM + t;
    if (pos >= gend - gbeg) { *op = 0.0f; return; }
    int g = gbeg + pos;
    int ns = lb_gid(gid, Ntot, g), ne = lb_gid(gid, Ntot, g + 1);
    float m = gmax[g], den = gden[g];
    float acc = 0.0f;
    for (int n = ns; n < ne; ++n) {
        float hv = __uint_as_float((unsigned)H[(size_t)n * FPAD + t] << 16);
        acc += expf(gate[n] - m) * hv;
    }
    *op = acc / den;
}

// ------------------------------------------------------------------ launcher

extern "C" void kernel_launch(void* const* d_in, const int* in_sizes, int n_in,
                              void* d_out, int out_size, void* d_ws, size_t ws_size,
                              hipStream_t stream) {
    const float* x      = (const float*)d_in[0];
    const float* Ws     = (const float*)d_in[1];
    const float* bs     = (const float*)d_in[2];
    const float* w_gate = (const float*)d_in[3];
    const float* b_gate = (const float*)d_in[4];
    const int* src       = (const int*)d_in[5];
    const int* dst       = (const int*)d_in[6];
    const int* graph_ids = (const int*)d_in[7];
    const int* num       = (const int*)d_in[8];
    float* out  = (float*)d_out;

    const int N  = in_sizes[7];
    const int E  = in_sizes[5];
    const int Bn = in_sizes[8];
    const int F  = in_sizes[3];            // 31
    const int L  = in_sizes[2] / F;        // 5
    const int nW = in_sizes[1];            // L * 3F * F
    const int WperL = nW / L;              // 3F*F
    const int MAXG = out_size / (Bn * F);  // 120
    const int Gmax = Bn * MAXG;

    const int nbuk = (N + CW - 1) / CW;    // 196 for N=400K
    const int cap  = E / nbuk + E / (8 * nbuk) + 2048;

    // ---- workspace carve-up
    char* p = (char*)d_ws;
    auto alloc = [&](size_t bytes) {
        void* r = (void*)p;
        p += (bytes + 255) & ~(size_t)255;
        return r;
    };
    // H arrays carry N+1 rows: row N is the all-zero dummy consumed by pad edges
    unsigned* HA = (unsigned*)alloc((size_t)(N + 1) * RSTRIDE * 4);
    unsigned* HB = (unsigned*)alloc((size_t)(N + 1) * RSTRIDE * 4);
    int*   colw  = (int*)alloc(((size_t)E + (size_t)nbuk * (7 * CW + 16)) * 4);  // padded CSR
    int*   bkt   = (int*)alloc((size_t)nbuk * cap * 4);
    int*   gcnt  = (int*)alloc((size_t)nbuk * 4);
    int*   bbase = (int*)alloc((size_t)nbuk * 4);
    int*   rowb  = (int*)alloc((size_t)(N + 1) * 4);
    int*   rowe  = (int*)alloc((size_t)(N + 1) * 4);
    float* normv = (float*)alloc((size_t)N * 4);
    float* invnv = (float*)alloc((size_t)N * 4);
    float* gatev = (float*)alloc((size_t)N * 4);
    float* gmax  = (float*)alloc((size_t)Gmax * 4);
    float* gden  = (float*)alloc((size_t)Gmax * 4);
    int*   soff  = (int*)alloc((size_t)(Bn + 1) * 4);

    // ---- zero init (only gcnt)
    (void)hipMemsetAsync(gcnt, 0, (size_t)nbuk * 4, stream);

    // ---- CSR build: multisplit -> tiny scans -> per-bucket build (3 kernels)
    const int NT = (E + TILE - 1) / TILE;
    multisplit_kernel<<<NT, 256, 0, stream>>>(src, dst, gcnt, bkt, cap, E, nbuk);
    small_scans_kernel<<<1, 64, 0, stream>>>(num, soff, Bn, gcnt, bbase, nbuk, cap);
    bucket_build_kernel<<<nbuk, 1024, 0, stream>>>(bkt, gcnt, bbase, rowb, rowe,
                                                   normv, invnv, colw, cap, N, nbuk);

    // ---- input layout (fp32 -> packed bf16 norm-scaled, pad 31 -> 32, zero row N)
    cast_x_kernel<<<((N + 1) * RSTRIDE + 255) / 256, 256, 0, stream>>>(x, normv, HA, N);

    // ---- 5 TAGConv layers: hop1 (HA->HB), fused hop2+MLP (HB,HA -> HA in place)
    const int SB  = (N + 1 + 63) / 64;     // +1 covers the dummy zero row
    const int SB2 = (N + 63) / 64;
    for (int l = 0; l < L; ++l) {
        spmm_kernel<<<SB, 256, 0, stream>>>(HA, HB, rowb, rowe, colw, normv, N);
        spmm_mlp_kernel<<<SB2, 256, 0, stream>>>(HB, HA, rowb, rowe, colw, normv, invnv,
                                                 Ws + (size_t)l * WperL, bs + (size_t)l * F,
                                                 gatev, w_gate, b_gate,
                                                 (l == L - 1) ? 1 : 0, N);
    }

    // ---- gated attention pooling + padded scatter (binary-search bounds)
    graph_reduce_kernel<<<Gmax, 64, 0, stream>>>(gatev, graph_ids, soff, Bn, N, gmax, gden);
    rep_scatter_kernel<<<Gmax, 64, 0, stream>>>((const unsigned short*)HA, gatev, graph_ids,
                                                soff, MAXG, N, gmax, gden, out);
    (void)n_in; (void)ws_size;
}

// Round 6
// 1556.251 us; speedup vs baseline: 1.2570x; 1.2570x over previous
//
#include <hip/hip_runtime.h>
#include <hip/hip_bf16.h>

// Problem constants (F is hard-coded 31 in the reference / TAG)
#define FDIM 31
#define FPAD 32      // padded row length in elements
#define RSTRIDE 16   // row stride in uints (32 bf16 = 64 B = 16 uints = 1 cache line)

// Coarse bucketing for CSR build: 2048 nodes per bucket
#define CBITS 11
#define CW    (1 << CBITS)
#define MAXBUK 256
#define TILE 4096

// clang ext-vector types: required by __builtin_nontemporal_{load,store}
// (HIP_vector_type int4/uint4 pointers are rejected by the builtin).
typedef int      iv4 __attribute__((ext_vector_type(4)));
typedef unsigned uv4 __attribute__((ext_vector_type(4)));

// ---- bf16 pack/unpack helpers (packed as 2 bf16 per uint, little-endian)
__device__ __forceinline__ float bf_lo(unsigned u) { return __uint_as_float(u << 16); }
__device__ __forceinline__ float bf_hi(unsigned u) { return __uint_as_float(u & 0xFFFF0000u); }
__device__ __forceinline__ unsigned pack2(float lo, float hi) {
    unsigned a = __float_as_uint(lo), b = __float_as_uint(hi);
    unsigned ra = (a + 0x7FFFu + ((a >> 16) & 1u)) >> 16;   // RNE
    unsigned rb = (b + 0x7FFFu + ((b >> 16) & 1u)) >> 16;
    return ra | (rb << 16);
}

// first index in sorted gid[0..Ntot) with gid[idx] >= g
__device__ __forceinline__ int lb_gid(const int* __restrict__ gid, int Ntot, int g) {
    int lo = 0, hi = Ntot;
    while (lo < hi) { int mid = (lo + hi) >> 1; if (gid[mid] < g) lo = mid + 1; else hi = mid; }
    return lo;
}

// --------------------------------------------------- multisplit (level 1)
__global__ __launch_bounds__(256) void multisplit_kernel(
    const int* __restrict__ src, const int* __restrict__ dst,
    int* __restrict__ gcnt, int* __restrict__ bucketed,
    int cap, int E, int nbuk)
{
    __shared__ int ordered[TILE];
    __shared__ int hist[MAXBUK];
    __shared__ int lofs[MAXBUK + 1];
    __shared__ int base_[MAXBUK];
    __shared__ int cur[MAXBUK];
    const int tid = threadIdx.x;
    const int e0 = blockIdx.x * TILE;
    const int n = min(TILE, E - e0);
    if (tid < MAXBUK) hist[tid] = 0;
    __syncthreads();
    for (int i = tid; i < n; i += 256)
        atomicAdd(&hist[dst[e0 + i] >> CBITS], 1);
    __syncthreads();
    if (tid == 0) {
        int a = 0;
        for (int b = 0; b < nbuk; ++b) { lofs[b] = a; a += hist[b]; }
        lofs[nbuk] = a;
    }
    __syncthreads();
    if (tid < nbuk) {
        int h = hist[tid];
        base_[tid] = h ? atomicAdd(&gcnt[tid], h) : 0;
        cur[tid] = lofs[tid];
    }
    __syncthreads();
    for (int i = tid; i < n; i += 256) {
        int s = src[e0 + i], d = dst[e0 + i];
        int b = d >> CBITS;
        int r = atomicAdd(&cur[b], 1);
        ordered[r] = (s << CBITS) | (d & (CW - 1));
    }
    __syncthreads();
    for (int i = tid; i < n; i += 256) {
        int lo = 0, hi = nbuk;
        while (hi - lo > 1) {
            int mid = (lo + hi) >> 1;
            if (lofs[mid] <= i) lo = mid; else hi = mid;
        }
        int b = lo;
        int pos = base_[b] + (i - lofs[b]);
        if (pos < cap) bucketed[(size_t)b * cap + pos] = ordered[i];
    }
}

// ---------------------------------- tiny serial scans: gcnt->bbase, num->soff
// bbase reserves room for per-row pad-to-8 (<= 7 per node, 2048 nodes/bucket)
// and is itself kept a multiple of 8 so every row start is 8-aligned (16B col).
__global__ void small_scans_kernel(const int* __restrict__ num, int* __restrict__ soff, int Bn,
                                   const int* __restrict__ gcnt, int* __restrict__ bbase,
                                   int nbuk, int cap) {
    if (threadIdx.x == 0 && blockIdx.x == 0) {
        int acc = 0; soff[0] = 0;
        for (int i = 0; i < Bn; ++i) { acc += num[i]; soff[i + 1] = acc; }
        int a = 0;
        for (int b = 0; b < nbuk; ++b) {
            bbase[b] = a;
            a += ((min(gcnt[b], cap) + 7) & ~7) + 7 * CW;
        }
    }
}

// -------------------- per-bucket: hist + LDS scan + rowbeg/rowend/normv + CSR fill
// Rows are padded to a multiple of 8 edges; pad slots point at dummy node N
// (whose feature row is all zeros) so the SpMM loop has NO scalar tail.
__global__ __launch_bounds__(1024) void bucket_build_kernel(
    const int* __restrict__ bucketed, const int* __restrict__ gcnt,
    const int* __restrict__ bbase,
    int* __restrict__ rowbeg, int* __restrict__ rowend,
    float* __restrict__ normv, float* __restrict__ invn,
    int* __restrict__ col,
    int cap, int N, int nbuk)
{
    __shared__ int hist[CW];   // counts -> padded counts -> inclusive scan
    __shared__ int lcur[CW];   // fill cursors
    const int b = blockIdx.x, tid = threadIdx.x;
    hist[tid] = 0; hist[tid + 1024] = 0;
    __syncthreads();
    const int cnt = min(gcnt[b], cap);
    const int* reg = bucketed + (size_t)b * cap;
    for (int i = tid; i < cnt; i += 1024)
        atomicAdd(&hist[reg[i] & (CW - 1)], 1);
    __syncthreads();
    int c0 = hist[tid], c1 = hist[tid + 1024];       // real per-node counts
    int p0 = (c0 + 7) & ~7, p1 = (c1 + 7) & ~7;      // padded to multiple of 8
    __syncthreads();
    hist[tid] = p0; hist[tid + 1024] = p1;           // scan PADDED counts
    __syncthreads();
    // Hillis-Steele inclusive scan over 2048 entries with 1024 threads
    for (int off = 1; off < CW; off <<= 1) {
        int a0 = (tid >= off) ? hist[tid - off] : 0;
        int a1 = (tid + 1024 >= off) ? hist[tid + 1024 - off] : 0;
        __syncthreads();
        hist[tid] += a0; hist[tid + 1024] += a1;
        __syncthreads();
    }
    const int base = bbase[b];
    const int base_node = b << CBITS;
    int r0 = -1, r1 = -1;
    int node = base_node + tid;
    if (node < N) {
        r0 = base + hist[tid] - p0;                  // exclusive padded prefix
        rowbeg[node] = r0; rowend[node] = r0 + p0; lcur[tid] = r0;
        int cr = c0 > 0 ? c0 : 1;
        normv[node] = rsqrtf((float)cr);
        invn[node]  = sqrtf((float)cr);
    }
    node = base_node + tid + 1024;
    if (node < N) {
        r1 = base + hist[tid + 1024] - p1;
        rowbeg[node] = r1; rowend[node] = r1 + p1; lcur[tid + 1024] = r1;
        int cr = c1 > 0 ? c1 : 1;
        normv[node] = rsqrtf((float)cr);
        invn[node]  = sqrtf((float)cr);
    }
    __syncthreads();
    for (int i = tid; i < cnt; i += 1024) {
        int e = reg[i];
        int p = atomicAdd(&lcur[e & (CW - 1)], 1);
        col[p] = e >> CBITS;
    }
    // pad slots -> dummy node N (disjoint from real slots: no sync needed)
    if (r0 >= 0) for (int j = r0 + c0; j < r0 + p0; ++j) col[j] = N;
    if (r1 >= 0) for (int j = r1 + c1; j < r1 + p1; ++j) col[j] = N;
}

// ---- fp32 x -> packed bf16 PRE-SCALED rows: HA[n] = norm[n] * x[n]
// Row N (the pad target) is all zeros. HA[N] is never rewritten afterwards
// (spmm_mlp phase B only writes nodes < N), so pad-gathers stay zero all run.
__global__ void cast_x_kernel(const float* __restrict__ x, const float* __restrict__ normv,
                              unsigned* __restrict__ A, int N) {
    int idx = blockIdx.x * 256 + threadIdx.x;
    if (idx >= (N + 1) * RSTRIDE) return;
    int n = idx >> 4, q = idx & 15;
    if (n >= N) { A[idx] = 0u; return; }
    float nv = normv[n];
    int f0 = 2 * q, f1 = 2 * q + 1;
    float lo = (f0 < FDIM) ? nv * x[(size_t)n * FDIM + f0] : 0.0f;
    float hi = (f1 < FDIM) ? nv * x[(size_t)n * FDIM + f1] : 0.0f;
    A[idx] = pack2(lo, hi);
}

// ---- gather/accumulate macro bodies
#define GATHER8(HSRC, r0, r1, r2, r3, r4, r5, r6, r7, CA, CB)                    \
    r0 = *((const uint4*)(HSRC + (size_t)(CA).x * RSTRIDE) + sub);               \
    r1 = *((const uint4*)(HSRC + (size_t)(CA).y * RSTRIDE) + sub);               \
    r2 = *((const uint4*)(HSRC + (size_t)(CA).z * RSTRIDE) + sub);               \
    r3 = *((const uint4*)(HSRC + (size_t)(CA).w * RSTRIDE) + sub);               \
    r4 = *((const uint4*)(HSRC + (size_t)(CB).x * RSTRIDE) + sub);               \
    r5 = *((const uint4*)(HSRC + (size_t)(CB).y * RSTRIDE) + sub);               \
    r6 = *((const uint4*)(HSRC + (size_t)(CB).z * RSTRIDE) + sub);               \
    r7 = *((const uint4*)(HSRC + (size_t)(CB).w * RSTRIDE) + sub);

#define ACC_EDGE(vN)                                                   \
    acc0 += bf_lo(vN.x); acc1 += bf_hi(vN.x);                          \
    acc2 += bf_lo(vN.y); acc3 += bf_hi(vN.y);                          \
    acc4 += bf_lo(vN.z); acc5 += bf_hi(vN.z);                          \
    acc6 += bf_lo(vN.w); acc7 += bf_hi(vN.w);

#define ACC8(r0, r1, r2, r3, r4, r5, r6, r7)                           \
    ACC_EDGE(r0) ACC_EDGE(r1) ACC_EDGE(r2) ACC_EDGE(r3)                \
    ACC_EDGE(r4) ACC_EDGE(r5) ACC_EDGE(r6) ACC_EDGE(r7)

// ------------------------------------------------------------------ SpMM hop1
// Storage invariant: Hin rows are norm-scaled (H~ = norm .* h), so a hop is
// H~out = norm^2 .* sum(H~in[col]). Rows padded to x8 with dummy node N.
// NOTE (R3 post-mortem): the random gather runs at a ~3.7 TB/s external
// ceiling insensitive to occupancy (47->55% with zero delta) and to deeper
// per-wave pipelining (2-deep pipeline: null). Treat ~113 us as this
// kernel's floor; do not re-spend rounds here without a bytes reduction.
__global__ __launch_bounds__(256) void spmm_kernel(const unsigned* __restrict__ Hin,
                                                   unsigned* __restrict__ Hout,
                                                   const int* __restrict__ rowbeg,
                                                   const int* __restrict__ rowend,
                                                   const int* __restrict__ col,
                                                   const float* __restrict__ normv, int N) {
    int node = blockIdx.x * 64 + (threadIdx.x >> 2);
    int sub = threadIdx.x & 3;
    if (node > N) return;
    if (node == N) {                       // dummy zero row consumed by pad edges
        uv4 z = (uv4)0;
        __builtin_nontemporal_store(z, (uv4*)(Hout + (size_t)N * RSTRIDE) + sub);
        return;
    }
    int s = rowbeg[node];
    int nit = (rowend[node] - s) >> 3;
    float acc0 = 0.f, acc1 = 0.f, acc2 = 0.f, acc3 = 0.f;
    float acc4 = 0.f, acc5 = 0.f, acc6 = 0.f, acc7 = 0.f;
    if (nit > 0) {
        const iv4* cl = (const iv4*)(col + s);      // 16B-aligned (rows 8-aligned)
        iv4 ca = __builtin_nontemporal_load(cl);
        iv4 cb = __builtin_nontemporal_load(cl + 1);
        for (int it = 0; it < nit; ++it) {
            uint4 v0, v1, v2, v3, v4, v5, v6, v7;
            GATHER8(Hin, v0, v1, v2, v3, v4, v5, v6, v7, ca, cb)
            const iv4* nx = cl + ((it + 1 < nit) ? 2 : 0);
            iv4 na = __builtin_nontemporal_load(nx);
            iv4 nb = __builtin_nontemporal_load(nx + 1);
            cl += 2;
            ACC8(v0, v1, v2, v3, v4, v5, v6, v7)
            ca = na; cb = nb;
        }
    }
    float nv = normv[node];
    float nn2 = nv * nv;                   // H~out = norm^2 * sum
    uv4 o;
    o.x = pack2(nn2 * acc0, nn2 * acc1);
    o.y = pack2(nn2 * acc2, nn2 * acc3);
    o.z = pack2(nn2 * acc4, nn2 * acc5);
    o.w = pack2(nn2 * acc6, nn2 * acc7);
    __builtin_nontemporal_store(o, (uv4*)(Hout + (size_t)node * RSTRIDE) + sub);
}

// ---- phase-B column-block worker. JB/NJ are TEMPLATE LITERALS so every
// W/bias/w_gate index is a compile-time offset from a uniform pointer ->
// provably uniform -> s_load. (R5 post-mortem: runtime readfirstlane + clamp
// broke uniformity analysis -> per-lane VMEM W loads -> VALU x2, gather BW
// -33%. Compile-time indices are the only proven-scalar pattern here.)
template<int JB, int NJ>
__device__ __forceinline__ void mlp_cols(const uint4 (&ra)[4], const uint4 (&rb)[4],
                                         const float* hp, const float* __restrict__ W,
                                         const float* __restrict__ bias,
                                         float inv, float sc, unsigned* orow,
                                         const float* __restrict__ w_gate,
                                         int do_gate, float& gp) {
    float out[8];
#pragma unroll
    for (int jj = 0; jj < 8; ++jj) out[jj] = 0.0f;
    {   // blk 0: ha (staged regs)
        const unsigned* ru = (const unsigned*)ra;
#pragma unroll
        for (int i = 0; i < FDIM; ++i) {
            float v = (i & 1) ? bf_hi(ru[i >> 1]) : bf_lo(ru[i >> 1]);
#pragma unroll
            for (int jj = 0; jj < NJ; ++jj)
                out[jj] = fmaf(v, W[i * FDIM + JB + jj], out[jj]);
        }
    }
    {   // blk 1: hb
        const unsigned* ru = (const unsigned*)rb;
#pragma unroll
        for (int i = 0; i < FDIM; ++i) {
            float v = (i & 1) ? bf_hi(ru[i >> 1]) : bf_lo(ru[i >> 1]);
#pragma unroll
            for (int jj = 0; jj < NJ; ++jj)
                out[jj] = fmaf(v, W[FDIM * FDIM + i * FDIM + JB + jj], out[jj]);
        }
    }
    {   // blk 2: hc (LDS, f32)
#pragma unroll
        for (int i = 0; i < FDIM; ++i) {
            float v = hp[i];
#pragma unroll
            for (int jj = 0; jj < NJ; ++jj)
                out[jj] = fmaf(v, W[2 * FDIM * FDIM + i * FDIM + JB + jj], out[jj]);
        }
    }
#pragma unroll
    for (int jj = 0; jj < NJ; ++jj)
        out[jj] = fmaxf(fmaf(out[jj], inv, bias[JB + jj]), 0.0f);
#pragma unroll
    for (int jj = NJ; jj < 8; ++jj) out[jj] = 0.0f;  // pad column (wave 3)
    uint4 q;
    q.x = pack2(sc * out[0], sc * out[1]);
    q.y = pack2(sc * out[2], sc * out[3]);
    q.z = pack2(sc * out[4], sc * out[5]);
    q.w = pack2(sc * out[6], sc * out[7]);
    ((uint4*)orow)[JB >> 3] = q;                     // disjoint 16B quarter
    if (do_gate) {
#pragma unroll
        for (int jj = 0; jj < NJ; ++jj)
            gp = fmaf(out[jj], w_gate[JB + jj], gp);
    }
}

// --------------------------------------------- fused SpMM hop2 + linear + relu
// Phase A (256 threads, 4 lanes/node, 64 nodes/block): hop-2 gather from Hb;
// result stays in f32 LDS (hc) -- no HC global buffer.
// Phase B (ALL 4 WAVES): wave w owns output columns 8w..8w+7 (template
// literal) for all 64 nodes; lane = node. Same total FMA work as the 1-wave
// version, 4x shorter wall. Hazard: Ha row read by all waves but written
// quarter-per-wave in place -> all Ha reads staged to regs before the
// barrier that precedes any write. Gate partials cross-wave-reduced in LDS.
__global__ __launch_bounds__(256, 5) void spmm_mlp_kernel(
    const unsigned* __restrict__ Hb,     // hop1 result (gather src + MLP input)
    unsigned* __restrict__ Ha,           // layer state (MLP input + output)
    const int* __restrict__ rowbeg,
    const int* __restrict__ rowend,
    const int* __restrict__ col,
    const float* __restrict__ normv,
    const float* __restrict__ invn,
    const float* __restrict__ W,         // this layer's 3*F*F block
    const float* __restrict__ bias,
    float* __restrict__ gatev,
    const float* __restrict__ w_gate,
    const float* __restrict__ b_gate,
    int do_gate, int N)
{
    __shared__ float hcL[64 * 33];       // stride 33: conflict-free both phases
    __shared__ float gred[256];          // gate partials (last layer only)
    const int tid = threadIdx.x;
    // ---------------- phase A: hop-2 gather -> hcL
    {
        int node = blockIdx.x * 64 + (tid >> 2);
        int sub = tid & 3;
        if (node < N) {
            int s = rowbeg[node];
            int nit = (rowend[node] - s) >> 3;
            float acc0 = 0.f, acc1 = 0.f, acc2 = 0.f, acc3 = 0.f;
            float acc4 = 0.f, acc5 = 0.f, acc6 = 0.f, acc7 = 0.f;
            if (nit > 0) {
                const iv4* cl = (const iv4*)(col + s);
                iv4 ca = __builtin_nontemporal_load(cl);
                iv4 cb = __builtin_nontemporal_load(cl + 1);
                for (int it = 0; it < nit; ++it) {
                    uint4 v0, v1, v2, v3, v4, v5, v6, v7;
                    GATHER8(Hb, v0, v1, v2, v3, v4, v5, v6, v7, ca, cb)
                    const iv4* nx = cl + ((it + 1 < nit) ? 2 : 0);
                    iv4 na = __builtin_nontemporal_load(nx);
                    iv4 nb = __builtin_nontemporal_load(nx + 1);
                    cl += 2;
                    ACC8(v0, v1, v2, v3, v4, v5, v6, v7)
                    ca = na; cb = nb;
                }
            }
            float nv = normv[node];
            float nn2 = nv * nv;
            float* hp = &hcL[(tid >> 2) * 33 + sub * 8];
            hp[0] = nn2 * acc0; hp[1] = nn2 * acc1;
            hp[2] = nn2 * acc2; hp[3] = nn2 * acc3;
            hp[4] = nn2 * acc4; hp[5] = nn2 * acc5;
            hp[6] = nn2 * acc6; hp[7] = nn2 * acc7;
        }
    }
    __syncthreads();                      // hcL ready
    // ---------------- phase B: wave = column block (template literal), lane = node
    const int ln = tid & 63;
    const int wv = tid >> 6;              // wave-uniform
    const int n2 = blockIdx.x * 64 + ln;
    // stage the Ha row BEFORE the barrier (in-place write hazard)
    uint4 ra[4];
    if (n2 < N) {
        const uint4* r4p = (const uint4*)(Ha + (size_t)n2 * RSTRIDE);
#pragma unroll
        for (int q = 0; q < 4; ++q) ra[q] = r4p[q];
    }
    __syncthreads();                      // all Ha reads done before any write
    float gp = 0.0f;
    if (n2 < N) {
        uint4 rb[4];
        const uint4* r4p = (const uint4*)(Hb + (size_t)n2 * RSTRIDE);
#pragma unroll
        for (int q = 0; q < 4; ++q) rb[q] = r4p[q];
        const float* hp = &hcL[ln * 33];
        float inv = invn[n2];
        float sc = do_gate ? 1.0f : normv[n2];       // next layer wants norm-scaled
        unsigned* orow = Ha + (size_t)n2 * RSTRIDE;
        if      (wv == 0) mlp_cols<0,  8>(ra, rb, hp, W, bias, inv, sc, orow, w_gate, do_gate, gp);
        else if (wv == 1) mlp_cols<8,  8>(ra, rb, hp, W, bias, inv, sc, orow, w_gate, do_gate, gp);
        else if (wv == 2) mlp_cols<16, 8>(ra, rb, hp, W, bias, inv, sc, orow, w_gate, do_gate, gp);
        else              mlp_cols<24, 7>(ra, rb, hp, W, bias, inv, sc, orow, w_gate, do_gate, gp);
    }
    if (do_gate) {
        gred[tid] = gp;
        __syncthreads();
        if (tid < 64 && n2 < N)
            gatev[n2] = b_gate[0] + gred[tid] + gred[tid + 64] + gred[tid + 128] + gred[tid + 192];
    }
}

// ----------------------------------------------------------------- pooling

__global__ __launch_bounds__(64) void graph_reduce_kernel(const float* __restrict__ gate,
                                                          const int* __restrict__ gid,
                                                          const int* __restrict__ soff, int Bn,
                                                          int Ntot,
                                                          float* __restrict__ gmax,
                                                          float* __restrict__ gden) {
    int g = blockIdx.x;
    if (g >= soff[Bn]) return;
    int s = lb_gid(gid, Ntot, g), e = lb_gid(gid, Ntot, g + 1);
    float m = -1e30f;
    for (int n = s + threadIdx.x; n < e; n += 64) m = fmaxf(m, gate[n]);
#pragma unroll
    for (int o = 32; o > 0; o >>= 1) m = fmaxf(m, __shfl_xor(m, o));
    float d = 0.0f;
    for (int n = s + threadIdx.x; n < e; n += 64) d += expf(gate[n] - m);
#pragma unroll
    for (int o = 32; o > 0; o >>= 1) d += __shfl_xor(d, o);
    if (threadIdx.x == 0) { gmax[g] = m; gden[g] = d; }
}

// One block per (sample, slot); writes zeros into pad slots (replaces d_out memset).
__global__ __launch_bounds__(64) void rep_scatter_kernel(const unsigned short* __restrict__ H,
                                                         const float* __restrict__ gate,
                                                         const int* __restrict__ gid,
                                                         const int* __restrict__ soff,
                                                         int MAXG, int Ntot,
                                                         const float* __restrict__ gmax,
                                                         const float* __restrict__ gden,
                                                         float* __restrict__ out) {
    int s = blockIdx.x / MAXG;
    int pos = blockIdx.x % MAXG;
    int t = threadIdx.x;
    if (t >= FDIM) return;
    int gbeg = soff[s], gend = soff[s + 1];
    float* op = out + ((size_t)s * MAXG + pos) * FDIM + t;
    if (pos >= gend - gbeg) { *op = 0.0f; return; }
    int g = gbeg + pos;
    int ns = lb_gid(gid, Ntot, g), ne = lb_gid(gid, Ntot, g + 1);
    float m = gmax[g], den = gden[g];
    float acc = 0.0f;
    for (int n = ns; n < ne; ++n) {
        float hv = __uint_as_float((unsigned)H[(size_t)n * FPAD + t] << 16);
        acc += expf(gate[n] - m) * hv;
    }
    *op = acc / den;
}

// ------------------------------------------------------------------ launcher

extern "C" void kernel_launch(void* const* d_in, const int* in_sizes, int n_in,
                              void* d_out, int out_size, void* d_ws, size_t ws_size,
                              hipStream_t stream) {
    const float* x      = (const float*)d_in[0];
    const float* Ws     = (const float*)d_in[1];
    const float* bs     = (const float*)d_in[2];
    const float* w_gate = (const float*)d_in[3];
    const float* b_gate = (const float*)d_in[4];
    const int* src       = (const int*)d_in[5];
    const int* dst       = (const int*)d_in[6];
    const int* graph_ids = (const int*)d_in[7];
    const int* num       = (const int*)d_in[8];
    float* out  = (float*)d_out;

    const int N  = in_sizes[7];
    const int E  = in_sizes[5];
    const int Bn = in_sizes[8];
    const int F  = in_sizes[3];            // 31
    const int L  = in_sizes[2] / F;        // 5
    const int nW = in_sizes[1];            // L * 3F * F
    const int WperL = nW / L;              // 3F*F
    const int MAXG = out_size / (Bn * F);  // 120
    const int Gmax = Bn * MAXG;

    const int nbuk = (N + CW - 1) / CW;    // 196 for N=400K
    const int cap  = E / nbuk + E / (8 * nbuk) + 2048;

    // ---- workspace carve-up
    char* p = (char*)d_ws;
    auto alloc = [&](size_t bytes) {
        void* r = (void*)p;
        p += (bytes + 255) & ~(size_t)255;
        return r;
    };
    // H arrays carry N+1 rows: row N is the all-zero dummy consumed by pad edges
    unsigned* HA = (unsigned*)alloc((size_t)(N + 1) * RSTRIDE * 4);
    unsigned* HB = (unsigned*)alloc((size_t)(N + 1) * RSTRIDE * 4);
    int*   colw  = (int*)alloc(((size_t)E + (size_t)nbuk * (7 * CW + 16)) * 4);  // padded CSR
    int*   bkt   = (int*)alloc((size_t)nbuk * cap * 4);
    int*   gcnt  = (int*)alloc((size_t)nbuk * 4);
    int*   bbase = (int*)alloc((size_t)nbuk * 4);
    int*   rowb  = (int*)alloc((size_t)(N + 1) * 4);
    int*   rowe  = (int*)alloc((size_t)(N + 1) * 4);
    float* normv = (float*)alloc((size_t)N * 4);
    float* invnv = (float*)alloc((size_t)N * 4);
    float* gatev = (float*)alloc((size_t)N * 4);
    float* gmax  = (float*)alloc((size_t)Gmax * 4);
    float* gden  = (float*)alloc((size_t)Gmax * 4);
    int*   soff  = (int*)alloc((size_t)(Bn + 1) * 4);

    // ---- zero init (only gcnt)
    (void)hipMemsetAsync(gcnt, 0, (size_t)nbuk * 4, stream);

    // ---- CSR build: multisplit -> tiny scans -> per-bucket build (3 kernels)
    const int NT = (E + TILE - 1) / TILE;
    multisplit_kernel<<<NT, 256, 0, stream>>>(src, dst, gcnt, bkt, cap, E, nbuk);
    small_scans_kernel<<<1, 64, 0, stream>>>(num, soff, Bn, gcnt, bbase, nbuk, cap);
    bucket_build_kernel<<<nbuk, 1024, 0, stream>>>(bkt, gcnt, bbase, rowb, rowe,
                                                   normv, invnv, colw, cap, N, nbuk);

    // ---- input layout (fp32 -> packed bf16 norm-scaled, pad 31 -> 32, zero row N)
    cast_x_kernel<<<((N + 1) * RSTRIDE + 255) / 256, 256, 0, stream>>>(x, normv, HA, N);

    // ---- 5 TAGConv layers: hop1 (HA->HB), fused hop2+MLP (HB,HA -> HA in place)
    const int SB  = (N + 1 + 63) / 64;     // +1 covers the dummy zero row
    const int SB2 = (N + 63) / 64;
    for (int l = 0; l < L; ++l) {
        spmm_kernel<<<SB, 256, 0, stream>>>(HA, HB, rowb, rowe, colw, normv, N);
        spmm_mlp_kernel<<<SB2, 256, 0, stream>>>(HB, HA, rowb, rowe, colw, normv, invnv,
                                                 Ws + (size_t)l * WperL, bs + (size_t)l * F,
                                                 gatev, w_gate, b_gate,
                                                 (l == L - 1) ? 1 : 0, N);
    }

    // ---- gated attention pooling + padded scatter (binary-search bounds)
    graph_reduce_kernel<<<Gmax, 64, 0, stream>>>(gatev, graph_ids, soff, Bn, N, gmax, gden);
    rep_scatter_kernel<<<Gmax, 64, 0, stream>>>((const unsigned short*)HA, gatev, graph_ids,
                                                soff, MAXG, N, gmax, gden, out);
    (void)n_in; (void)ws_size;
}